// Round 2
// baseline (687.535 us; speedup 1.0000x reference)
//
#include <hip/hip_runtime.h>

// ROI Align, fp32 NCHW. x: (8,256,100,152), rois: (1000,5), out: (1000,256,7,7)
// Thread = one (roi, channel); all coordinate/weight math is wave-uniform
// (lane only selects channel) -> SGPR-friendly. Per-lane work is only the
// corner gathers (stride H*W across lanes -> line-per-lane scatter; TA-bound).
// This revision: (a) x-corner pairs loaded as one 8B load (x1 == x0+1 except
// at the uniform right edge, handled by min(x0,W-2) + uniform select);
// (b) pw loop fully unrolled for load-latency hiding.

namespace {
constexpr int C = 256, H = 100, W = 152;
constexpr int PH = 7, PW = 7;
constexpr float SCALE = 1.0f / 16.0f;
constexpr int CPB = 64;  // channels per block (one wave)
typedef float v2f __attribute__((ext_vector_type(2), aligned(4)));  // 4B-aligned float2
}

__global__ __launch_bounds__(CPB, 4) void roi_align_kernel(
    const float* __restrict__ x, const float* __restrict__ rois,
    float* __restrict__ out) {
  const int r = blockIdx.x;
  const int c = blockIdx.y * CPB + threadIdx.x;

  const float* roi = rois + r * 5;
  const int b = (int)roi[0];
  const float sx1 = roi[1] * SCALE;
  const float sy1 = roi[2] * SCALE;
  const float sx2 = roi[3] * SCALE;
  const float sy2 = roi[4] * SCALE;
  const float bin_w = fmaxf(sx2 - sx1, 1.0f) * (1.0f / (float)PW);
  const float bin_h = fmaxf(sy2 - sy1, 1.0f) * (1.0f / (float)PH);

  const float* __restrict__ xb = x + ((size_t)b * C + c) * (size_t)(H * W);
  float* __restrict__ ob = out + ((size_t)r * C + c) * (size_t)(PH * PW);

  // Precompute x-sample data for all 7*2 samples (wave-uniform).
  int xm[PW][2];        // min(x0, W-2): base of the 8B pair load
  bool xe[PW][2];       // x0 == W-1 (right-edge clamp)
  float lx[PW][2], hx[PW][2], vx[PW][2];
#pragma unroll
  for (int pw = 0; pw < PW; ++pw) {
#pragma unroll
    for (int s = 0; s < 2; ++s) {
      float xx = sx1 + ((float)pw + 0.25f + 0.5f * (float)s) * bin_w;
      vx[pw][s] = (xx >= -1.0f && xx <= (float)W) ? 1.0f : 0.0f;
      float xc = fminf(fmaxf(xx, 0.0f), (float)(W - 1));
      int xi = (int)xc;  // xc >= 0 -> trunc == floor
      xm[pw][s] = min(xi, W - 2);
      xe[pw][s] = (xi == W - 1);
      lx[pw][s] = xc - (float)xi;
      hx[pw][s] = 1.0f - lx[pw][s];
    }
  }

  for (int ph = 0; ph < PH; ++ph) {
    // y-sample data for this pooled row (2 samples), wave-uniform
    const float* r0[2];
    const float* r1[2];
    float ly[2], hy[2], vy[2];
#pragma unroll
    for (int s = 0; s < 2; ++s) {
      float yy = sy1 + ((float)ph + 0.25f + 0.5f * (float)s) * bin_h;
      vy[s] = (yy >= -1.0f && yy <= (float)H) ? 1.0f : 0.0f;
      float yc = fminf(fmaxf(yy, 0.0f), (float)(H - 1));
      int yi = (int)yc;
      r0[s] = xb + yi * W;
      r1[s] = xb + min(yi + 1, H - 1) * W;
      ly[s] = yc - (float)yi;
      hy[s] = 1.0f - ly[s];
    }
#pragma unroll
    for (int pw = 0; pw < PW; ++pw) {
      float acc = 0.0f;
#pragma unroll
      for (int sy = 0; sy < 2; ++sy) {
#pragma unroll
        for (int sx = 0; sx < 2; ++sx) {
          const int xi = xm[pw][sx];
          // 8B pair loads: [xi, xi+1] on both bilinear rows
          v2f p0 = *(const v2f*)(r0[sy] + xi);
          v2f p1 = *(const v2f*)(r1[sy] + xi);
          // right-edge: pair is [W-2, W-1]; v00/v10 must be the W-1 value,
          // and the x1 terms get weight lx == 0, so p?.y there is harmless.
          float v00 = xe[pw][sx] ? p0.y : p0.x;
          float v01 = p0.y;
          float v10 = xe[pw][sx] ? p1.y : p1.x;
          float v11 = p1.y;
          float v = (hy[sy] * hx[pw][sx]) * v00 + (hy[sy] * lx[pw][sx]) * v01 +
                    (ly[sy] * hx[pw][sx]) * v10 + (ly[sy] * lx[pw][sx]) * v11;
          acc += vy[sy] * vx[pw][sx] * v;
        }
      }
      ob[ph * PW + pw] = acc * 0.25f;  // mean over the 4 samples
    }
  }
}

extern "C" void kernel_launch(void* const* d_in, const int* in_sizes, int n_in,
                              void* d_out, int out_size, void* d_ws, size_t ws_size,
                              hipStream_t stream) {
  const float* x = (const float*)d_in[0];
  const float* rois = (const float*)d_in[1];
  float* out = (float*)d_out;
  const int R = in_sizes[1] / 5;  // 1000
  dim3 grid((unsigned)R, (unsigned)(C / CPB));
  roi_align_kernel<<<grid, CPB, 0, stream>>>(x, rois, out);
}

// Round 6
// 280.993 us; speedup vs baseline: 2.4468x; 2.4468x over previous
//
#include <hip/hip_runtime.h>

// ROI Align, fp32. x: (8,256,100,152) NCHW, rois: (1000,5), out: (1000,256,7,7)
//
// R2 counters (NCHW gather): FETCH=1.58GB (13x input), WRITE=149MB (3x out),
// dur 553us -> L2-miss/fabric bound from line-per-lane gather scatter.
// Fix: transpose to NHWC in d_ws, then gather with lane=channel (fully
// coalesced 1024B corner loads), output staged in LDS, contiguous writeback.

namespace {
constexpr int C = 256, H = 100, W = 152;
constexpr int HW = H * W;          // 15200
constexpr int PH = 7, PW = 7;
constexpr float SCALE = 1.0f / 16.0f;
typedef float v2f __attribute__((ext_vector_type(2), aligned(4)));
}

// ---- Pass 1: NCHW -> NHWC tiled transpose (per batch: (C,HW) -> (HW,C)) ----
__global__ __launch_bounds__(256) void transpose_kernel(
    const float* __restrict__ x, float* __restrict__ xt) {
  __shared__ float tile[64][65];
  const int b = blockIdx.z;
  const int hw0 = blockIdx.x * 64;
  const int c0 = blockIdx.y * 64;
  const int tx = threadIdx.x & 63;
  const int ty = threadIdx.x >> 6;  // 0..3

  const float* src = x + (size_t)b * C * HW;
  float* dst = xt + (size_t)b * HW * C;

#pragma unroll
  for (int i = 0; i < 16; ++i) {
    const int cc = c0 + ty + 4 * i;     // < 256 always
    const int hw = hw0 + tx;
    if (hw < HW) tile[ty + 4 * i][tx] = src[(size_t)cc * HW + hw];
  }
  __syncthreads();
#pragma unroll
  for (int i = 0; i < 16; ++i) {
    const int hw = hw0 + ty + 4 * i;
    const int cc = c0 + tx;
    if (hw < HW) dst[(size_t)hw * C + cc] = tile[tx][ty + 4 * i];
  }
}

// ---- Pass 2: ROI align on NHWC; lane = channel; LDS-staged output ----
__global__ __launch_bounds__(256, 3) void roi_align_nhwc(
    const float* __restrict__ xt, const float* __restrict__ rois,
    float* __restrict__ out) {
  __shared__ float obuf[C * PH * PW];  // 50 KB, laid out [c][bin] == out layout
  const int r = blockIdx.x;
  const int c = threadIdx.x;

  const float* roi = rois + r * 5;
  const int b = (int)roi[0];
  const float sx1 = roi[1] * SCALE;
  const float sy1 = roi[2] * SCALE;
  const float sx2 = roi[3] * SCALE;
  const float sy2 = roi[4] * SCALE;
  const float bin_w = fmaxf(sx2 - sx1, 1.0f) / (float)PW;  // match ref exactly
  const float bin_h = fmaxf(sy2 - sy1, 1.0f) / (float)PH;

  const float* __restrict__ base = xt + (size_t)b * HW * C + c;

  // Precompute all 14 x-samples (wave-uniform values).
  int xo0[PW * 2], xo1[PW * 2];
  float lx[PW * 2], hx[PW * 2], vx[PW * 2];
#pragma unroll
  for (int i = 0; i < PW * 2; ++i) {
    const int pw = i >> 1, s = i & 1;
    const float xx = sx1 + ((float)pw + 0.25f + 0.5f * (float)s) * bin_w;
    vx[i] = (xx >= -1.0f && xx <= (float)W) ? 1.0f : 0.0f;
    const float xc = fminf(fmaxf(xx, 0.0f), (float)(W - 1));
    const int xi = (int)xc;  // xc >= 0 -> trunc == floor
    xo0[i] = xi * C;
    xo1[i] = min(xi + 1, W - 1) * C;
    lx[i] = xc - (float)xi;
    hx[i] = 1.0f - lx[i];
  }

  for (int ph = 0; ph < PH; ++ph) {
    const float* __restrict__ ry0a;
    const float* __restrict__ ry0b;
    const float* __restrict__ ry1a;
    const float* __restrict__ ry1b;
    float ly_[2], hy_[2], vy_[2];
    {
      const float yyA = sy1 + ((float)ph + 0.25f) * bin_h;
      const float yyB = sy1 + ((float)ph + 0.75f) * bin_h;
      vy_[0] = (yyA >= -1.0f && yyA <= (float)H) ? 1.0f : 0.0f;
      vy_[1] = (yyB >= -1.0f && yyB <= (float)H) ? 1.0f : 0.0f;
      const float ycA = fminf(fmaxf(yyA, 0.0f), (float)(H - 1));
      const float ycB = fminf(fmaxf(yyB, 0.0f), (float)(H - 1));
      const int yiA = (int)ycA, yiB = (int)ycB;
      ry0a = base + (size_t)yiA * (W * C);
      ry1a = base + (size_t)min(yiA + 1, H - 1) * (W * C);
      ry0b = base + (size_t)yiB * (W * C);
      ry1b = base + (size_t)min(yiB + 1, H - 1) * (W * C);
      ly_[0] = ycA - (float)yiA; hy_[0] = 1.0f - ly_[0];
      ly_[1] = ycB - (float)yiB; hy_[1] = 1.0f - ly_[1];
    }
#pragma unroll
    for (int pw = 0; pw < PW; ++pw) {
      const int i0 = pw * 2, i1 = pw * 2 + 1;
      // Issue all 16 corner loads first (independent -> deep MLP), then FMAs.
      const float a00 = ry0a[xo0[i0]], a01 = ry0a[xo1[i0]];
      const float a10 = ry1a[xo0[i0]], a11 = ry1a[xo1[i0]];
      const float b00 = ry0a[xo0[i1]], b01 = ry0a[xo1[i1]];
      const float b10 = ry1a[xo0[i1]], b11 = ry1a[xo1[i1]];
      const float c00 = ry0b[xo0[i0]], c01 = ry0b[xo1[i0]];
      const float c10 = ry1b[xo0[i0]], c11 = ry1b[xo1[i0]];
      const float d00 = ry0b[xo0[i1]], d01 = ry0b[xo1[i1]];
      const float d10 = ry1b[xo0[i1]], d11 = ry1b[xo1[i1]];

      float acc;
      {
        const float vA = (hy_[0] * hx[i0]) * a00 + (hy_[0] * lx[i0]) * a01 +
                         (ly_[0] * hx[i0]) * a10 + (ly_[0] * lx[i0]) * a11;
        const float vB = (hy_[0] * hx[i1]) * b00 + (hy_[0] * lx[i1]) * b01 +
                         (ly_[0] * hx[i1]) * b10 + (ly_[0] * lx[i1]) * b11;
        const float vC = (hy_[1] * hx[i0]) * c00 + (hy_[1] * lx[i0]) * c01 +
                         (ly_[1] * hx[i0]) * c10 + (ly_[1] * lx[i0]) * c11;
        const float vD = (hy_[1] * hx[i1]) * d00 + (hy_[1] * lx[i1]) * d01 +
                         (ly_[1] * hx[i1]) * d10 + (ly_[1] * lx[i1]) * d11;
        acc = vy_[0] * vx[i0] * vA + vy_[0] * vx[i1] * vB +
              vy_[1] * vx[i0] * vC + vy_[1] * vx[i1] * vD;
      }
      obuf[c * (PH * PW) + ph * PW + pw] = acc * 0.25f;
    }
  }
  __syncthreads();
  // Contiguous coalesced writeback of the whole (256 ch x 49 bin) tile.
  float* o = out + (size_t)r * (C * PH * PW);
#pragma unroll
  for (int i = 0; i < (C * PH * PW) / 256; ++i)
    o[i * 256 + threadIdx.x] = obuf[i * 256 + threadIdx.x];
}

// ---- Fallback (ws too small): round-1 NCHW kernel ----
__global__ __launch_bounds__(64, 4) void roi_align_nchw(
    const float* __restrict__ x, const float* __restrict__ rois,
    float* __restrict__ out) {
  const int r = blockIdx.x;
  const int c = blockIdx.y * 64 + threadIdx.x;
  const float* roi = rois + r * 5;
  const int b = (int)roi[0];
  const float sx1 = roi[1] * SCALE, sy1 = roi[2] * SCALE;
  const float sx2 = roi[3] * SCALE, sy2 = roi[4] * SCALE;
  const float bin_w = fmaxf(sx2 - sx1, 1.0f) / (float)PW;
  const float bin_h = fmaxf(sy2 - sy1, 1.0f) / (float)PH;
  const float* __restrict__ xb = x + ((size_t)b * C + c) * (size_t)HW;
  float* __restrict__ ob = out + ((size_t)r * C + c) * (size_t)(PH * PW);
  int xm[PW][2];
  bool xe[PW][2];
  float lx[PW][2], hx[PW][2], vx[PW][2];
#pragma unroll
  for (int pw = 0; pw < PW; ++pw)
#pragma unroll
    for (int s = 0; s < 2; ++s) {
      float xx = sx1 + ((float)pw + 0.25f + 0.5f * (float)s) * bin_w;
      vx[pw][s] = (xx >= -1.0f && xx <= (float)W) ? 1.0f : 0.0f;
      float xc = fminf(fmaxf(xx, 0.0f), (float)(W - 1));
      int xi = (int)xc;
      xm[pw][s] = min(xi, W - 2);
      xe[pw][s] = (xi == W - 1);
      lx[pw][s] = xc - (float)xi;
      hx[pw][s] = 1.0f - lx[pw][s];
    }
  for (int ph = 0; ph < PH; ++ph) {
    const float* r0[2];
    const float* r1[2];
    float ly[2], hy[2], vy[2];
#pragma unroll
    for (int s = 0; s < 2; ++s) {
      float yy = sy1 + ((float)ph + 0.25f + 0.5f * (float)s) * bin_h;
      vy[s] = (yy >= -1.0f && yy <= (float)H) ? 1.0f : 0.0f;
      float yc = fminf(fmaxf(yy, 0.0f), (float)(H - 1));
      int yi = (int)yc;
      r0[s] = xb + yi * W;
      r1[s] = xb + min(yi + 1, H - 1) * W;
      ly[s] = yc - (float)yi;
      hy[s] = 1.0f - ly[s];
    }
#pragma unroll
    for (int pw = 0; pw < PW; ++pw) {
      float acc = 0.0f;
#pragma unroll
      for (int sy = 0; sy < 2; ++sy)
#pragma unroll
        for (int sx = 0; sx < 2; ++sx) {
          const int xi = xm[pw][sx];
          v2f p0 = *(const v2f*)(r0[sy] + xi);
          v2f p1 = *(const v2f*)(r1[sy] + xi);
          float v00 = xe[pw][sx] ? p0.y : p0.x;
          float v10 = xe[pw][sx] ? p1.y : p1.x;
          float v = (hy[sy] * hx[pw][sx]) * v00 + (hy[sy] * lx[pw][sx]) * p0.y +
                    (ly[sy] * hx[pw][sx]) * v10 + (ly[sy] * lx[pw][sx]) * p1.y;
          acc += vy[sy] * vx[pw][sx] * v;
        }
      ob[ph * PW + pw] = acc * 0.25f;
    }
  }
}

extern "C" void kernel_launch(void* const* d_in, const int* in_sizes, int n_in,
                              void* d_out, int out_size, void* d_ws, size_t ws_size,
                              hipStream_t stream) {
  const float* x = (const float*)d_in[0];
  const float* rois = (const float*)d_in[1];
  float* out = (float*)d_out;
  const int R = in_sizes[1] / 5;            // 1000
  const int B = in_sizes[0] / (C * HW);     // 8
  const size_t xt_bytes = (size_t)in_sizes[0] * sizeof(float);

  if (ws_size >= xt_bytes) {
    float* xt = (float*)d_ws;
    dim3 tgrid((HW + 63) / 64, C / 64, B);
    transpose_kernel<<<tgrid, 256, 0, stream>>>(x, xt);
    roi_align_nhwc<<<dim3((unsigned)R), 256, 0, stream>>>(xt, rois, out);
  } else {
    dim3 grid((unsigned)R, C / 64);
    roi_align_nchw<<<grid, 64, 0, stream>>>(x, rois, out);
  }
}